// Round 2
// baseline (83.723 us; speedup 1.0000x reference)
//
#include <hip/hip_runtime.h>

// Problem constants (fixed by setup_inputs): B=8, N=4096, K=3, V=100000,
// H=1024, SEQ=2048. H hard-coded; rest derived from in_sizes.
#define CAP 8       // max sets per (b, pos); dataset has exactly 2
#define MAXK 8      // max trigram ids per set we support in LDS fallback

// Phase 1: scatter each set's token ids into the per-(b,pos) token table.
__global__ void build_map_kernel(const int* __restrict__ pos_ids,
                                 const int* __restrict__ tok,
                                 int total, int n_per, int seq, int K,
                                 int* __restrict__ counts,
                                 int* __restrict__ toktab) {
    int i = blockIdx.x * blockDim.x + threadIdx.x;
    if (i >= total) return;
    int b = i / n_per;
    int p = pos_ids[i];
    if ((unsigned)p >= (unsigned)seq) return;
    int bp = b * seq + p;
    int c = atomicAdd(&counts[bp], 1);
    if (c < CAP) {
        int* dst = toktab + (size_t)bp * (CAP * K) + c * K;
        for (int k = 0; k < K; ++k) dst[k] = tok[i * K + k];
    }
}

#define SORT2(a, b) { int _lo = min(a, b); int _hi = max(a, b); a = _lo; b = _hi; }

// Phase 2: one block per output row (b,pos). Read count + token ids from one
// cache line, sort for deterministic FP order, gather W rows, normalize, store.
__global__ void gather_out_kernel(const float* __restrict__ W,
                                  const int* __restrict__ counts,
                                  const int* __restrict__ toktab,
                                  float* __restrict__ out,
                                  int K, int H) {
    int bp = blockIdx.x;
    int cnt = counts[bp];
    int ce = cnt < CAP ? cnt : CAP;
    int ntok = ce * K;
    const int* tp = toktab + (size_t)bp * (CAP * K);
    int h = threadIdx.x * 4;  // blockDim.x == H/4

    float4 acc = make_float4(0.f, 0.f, 0.f, 0.f);

    if (ntok == 6) {
        // Fast path (2 sets x K=3): register sort network, no LDS, no sync.
        int t0 = tp[0], t1 = tp[1], t2 = tp[2], t3 = tp[3], t4 = tp[4], t5 = tp[5];
        SORT2(t1, t2) SORT2(t4, t5) SORT2(t0, t2) SORT2(t3, t5)
        SORT2(t0, t1) SORT2(t3, t4) SORT2(t1, t4) SORT2(t0, t3)
        SORT2(t2, t5) SORT2(t1, t3) SORT2(t2, t4) SORT2(t2, t3)
        const float4 v0 = *(const float4*)(W + (size_t)t0 * H + h);
        const float4 v1 = *(const float4*)(W + (size_t)t1 * H + h);
        const float4 v2 = *(const float4*)(W + (size_t)t2 * H + h);
        const float4 v3 = *(const float4*)(W + (size_t)t3 * H + h);
        const float4 v4 = *(const float4*)(W + (size_t)t4 * H + h);
        const float4 v5 = *(const float4*)(W + (size_t)t5 * H + h);
        acc.x = ((v0.x + v1.x) + (v2.x + v3.x)) + (v4.x + v5.x);
        acc.y = ((v0.y + v1.y) + (v2.y + v3.y)) + (v4.y + v5.y);
        acc.z = ((v0.z + v1.z) + (v2.z + v3.z)) + (v4.z + v5.z);
        acc.w = ((v0.w + v1.w) + (v2.w + v3.w)) + (v4.w + v5.w);
    } else if (ntok > 0) {
        // General path: thread-0 insertion sort in LDS, then accumulate.
        __shared__ int s_tok[CAP * MAXK];
        if (threadIdx.x == 0) {
            for (int j = 0; j < ntok; ++j) s_tok[j] = tp[j];
            for (int a = 1; a < ntok; ++a) {
                int v = s_tok[a];
                int q = a - 1;
                while (q >= 0 && s_tok[q] > v) { s_tok[q + 1] = s_tok[q]; --q; }
                s_tok[q + 1] = v;
            }
        }
        __syncthreads();
        for (int j = 0; j < ntok; ++j) {
            int t = s_tok[j];
            const float4 v = *(const float4*)(W + (size_t)t * H + h);
            acc.x += v.x; acc.y += v.y; acc.z += v.z; acc.w += v.w;
        }
    }

    float denom = (float)K * (float)(cnt > 0 ? cnt : 1);
    float scale = 1.0f / denom;
    acc.x *= scale; acc.y *= scale; acc.z *= scale; acc.w *= scale;
    *(float4*)(out + (size_t)bp * H + h) = acc;
}

extern "C" void kernel_launch(void* const* d_in, const int* in_sizes, int n_in,
                              void* d_out, int out_size, void* d_ws, size_t ws_size,
                              hipStream_t stream) {
    const int*   pos_ids = (const int*)d_in[0];   // [B*N] int32
    const int*   tok     = (const int*)d_in[1];   // [B*N*K] int32
    // d_in[2]: offsets [B,2]; d_in[3]: seq_len scalar (derived on host)
    const float* W       = (const float*)d_in[4]; // [V*H] f32
    float*       out     = (float*)d_out;         // [B*SEQ*H] f32

    const int B     = in_sizes[2] / 2;
    const int total = in_sizes[0];        // B*N sets
    const int n_per = total / B;          // N
    const int K     = in_sizes[1] / total;
    const int H     = 1024;
    const int seq   = out_size / (B * H);

    int* counts = (int*)d_ws;                               // [B*seq]
    int* toktab = counts + (size_t)B * seq;                 // [B*seq*CAP*K]

    hipMemsetAsync(counts, 0, (size_t)B * seq * sizeof(int), stream);

    int bthreads = 256;
    int bblocks  = (total + bthreads - 1) / bthreads;
    build_map_kernel<<<bblocks, bthreads, 0, stream>>>(pos_ids, tok, total,
                                                       n_per, seq, K,
                                                       counts, toktab);

    gather_out_kernel<<<B * seq, H / 4, 0, stream>>>(W, counts, toktab,
                                                     out, K, H);
}

// Round 3
// 83.507 us; speedup vs baseline: 1.0026x; 1.0026x over previous
//
#include <hip/hip_runtime.h>

// Problem constants (fixed by setup_inputs): B=8, N=4096, K=3, V=100000,
// H=1024, SEQ=2048. H hard-coded; rest derived from in_sizes.
#define CAP 8       // max sets per (b, pos); dataset has exactly 2
#define MAXK 8      // max trigram ids per set we support in LDS fallback

// Phase 1: scatter each set's token ids into the per-(b,pos) token table.
__global__ void build_map_kernel(const int* __restrict__ pos_ids,
                                 const int* __restrict__ tok,
                                 int total, int n_per, int seq, int K,
                                 int* __restrict__ counts,
                                 int* __restrict__ toktab) {
    int i = blockIdx.x * blockDim.x + threadIdx.x;
    if (i >= total) return;
    int b = i / n_per;
    int p = __builtin_nontemporal_load(pos_ids + i);
    if ((unsigned)p >= (unsigned)seq) return;
    int bp = b * seq + p;
    int c = atomicAdd(&counts[bp], 1);
    if (c < CAP) {
        int* dst = toktab + (size_t)bp * (CAP * K) + c * K;
        for (int k = 0; k < K; ++k)
            dst[k] = __builtin_nontemporal_load(tok + i * K + k);
    }
}

#define SORT2(a, b) { int _lo = min(a, b); int _hi = max(a, b); a = _lo; b = _hi; }

// Phase 2: one block per output row (b,pos). Read count + token ids from one
// cache line, sort for deterministic FP order, gather W rows, normalize, store.
// Output stored non-temporally so the streaming write doesn't evict W from
// L2/L3 (W's unique footprint ~256 MB ~= L3 size; repeats should hit cache).
__global__ void gather_out_kernel(const float* __restrict__ W,
                                  const int* __restrict__ counts,
                                  const int* __restrict__ toktab,
                                  float* __restrict__ out,
                                  int K, int H) {
    int bp = blockIdx.x;
    int cnt = counts[bp];
    int ce = cnt < CAP ? cnt : CAP;
    int ntok = ce * K;
    const int* tp = toktab + (size_t)bp * (CAP * K);
    int h = threadIdx.x * 4;  // blockDim.x == H/4

    float4 acc = make_float4(0.f, 0.f, 0.f, 0.f);

    if (ntok == 6) {
        // Fast path (2 sets x K=3): register sort network, no LDS, no sync.
        int t0 = __builtin_nontemporal_load(tp + 0);
        int t1 = __builtin_nontemporal_load(tp + 1);
        int t2 = __builtin_nontemporal_load(tp + 2);
        int t3 = __builtin_nontemporal_load(tp + 3);
        int t4 = __builtin_nontemporal_load(tp + 4);
        int t5 = __builtin_nontemporal_load(tp + 5);
        SORT2(t1, t2) SORT2(t4, t5) SORT2(t0, t2) SORT2(t3, t5)
        SORT2(t0, t1) SORT2(t3, t4) SORT2(t1, t4) SORT2(t0, t3)
        SORT2(t2, t5) SORT2(t1, t3) SORT2(t2, t4) SORT2(t2, t3)
        const float4 v0 = *(const float4*)(W + (size_t)t0 * H + h);
        const float4 v1 = *(const float4*)(W + (size_t)t1 * H + h);
        const float4 v2 = *(const float4*)(W + (size_t)t2 * H + h);
        const float4 v3 = *(const float4*)(W + (size_t)t3 * H + h);
        const float4 v4 = *(const float4*)(W + (size_t)t4 * H + h);
        const float4 v5 = *(const float4*)(W + (size_t)t5 * H + h);
        acc.x = ((v0.x + v1.x) + (v2.x + v3.x)) + (v4.x + v5.x);
        acc.y = ((v0.y + v1.y) + (v2.y + v3.y)) + (v4.y + v5.y);
        acc.z = ((v0.z + v1.z) + (v2.z + v3.z)) + (v4.z + v5.z);
        acc.w = ((v0.w + v1.w) + (v2.w + v3.w)) + (v4.w + v5.w);
    } else if (ntok > 0) {
        // General path: thread-0 insertion sort in LDS, then accumulate.
        __shared__ int s_tok[CAP * MAXK];
        if (threadIdx.x == 0) {
            for (int j = 0; j < ntok; ++j) s_tok[j] = tp[j];
            for (int a = 1; a < ntok; ++a) {
                int v = s_tok[a];
                int q = a - 1;
                while (q >= 0 && s_tok[q] > v) { s_tok[q + 1] = s_tok[q]; --q; }
                s_tok[q + 1] = v;
            }
        }
        __syncthreads();
        for (int j = 0; j < ntok; ++j) {
            int t = s_tok[j];
            const float4 v = *(const float4*)(W + (size_t)t * H + h);
            acc.x += v.x; acc.y += v.y; acc.z += v.z; acc.w += v.w;
        }
    }

    float denom = (float)K * (float)(cnt > 0 ? cnt : 1);
    float scale = 1.0f / denom;
    acc.x *= scale; acc.y *= scale; acc.z *= scale; acc.w *= scale;
    float* op = out + (size_t)bp * H + h;
    __builtin_nontemporal_store(acc.x, op + 0);
    __builtin_nontemporal_store(acc.y, op + 1);
    __builtin_nontemporal_store(acc.z, op + 2);
    __builtin_nontemporal_store(acc.w, op + 3);
}

extern "C" void kernel_launch(void* const* d_in, const int* in_sizes, int n_in,
                              void* d_out, int out_size, void* d_ws, size_t ws_size,
                              hipStream_t stream) {
    const int*   pos_ids = (const int*)d_in[0];   // [B*N] int32
    const int*   tok     = (const int*)d_in[1];   // [B*N*K] int32
    // d_in[2]: offsets [B,2]; d_in[3]: seq_len scalar (derived on host)
    const float* W       = (const float*)d_in[4]; // [V*H] f32
    float*       out     = (float*)d_out;         // [B*SEQ*H] f32

    const int B     = in_sizes[2] / 2;
    const int total = in_sizes[0];        // B*N sets
    const int n_per = total / B;          // N
    const int K     = in_sizes[1] / total;
    const int H     = 1024;
    const int seq   = out_size / (B * H);

    int* counts = (int*)d_ws;                               // [B*seq]
    int* toktab = counts + (size_t)B * seq;                 // [B*seq*CAP*K]

    hipMemsetAsync(counts, 0, (size_t)B * seq * sizeof(int), stream);

    int bthreads = 256;
    int bblocks  = (total + bthreads - 1) / bthreads;
    build_map_kernel<<<bblocks, bthreads, 0, stream>>>(pos_ids, tok, total,
                                                       n_per, seq, K,
                                                       counts, toktab);

    gather_out_kernel<<<B * seq, H / 4, 0, stream>>>(W, counts, toktab,
                                                     out, K, H);
}